// Round 1
// baseline (326.244 us; speedup 1.0000x reference)
//
#include <hip/hip_runtime.h>
#include <stdint.h>

#define B_ 4
#define L_ 2048
#define H_ 8
#define E_ 64
#define S_ 2048
#define QT 16
#define SROW 2056  // 2048 + 8 halves pad -> row stride 4112 B (16B-aligned, bank-staggered)

typedef __bf16 bf16x8 __attribute__((ext_vector_type(8)));
typedef _Float16 f16x8 __attribute__((ext_vector_type(8)));
typedef float f32x4 __attribute__((ext_vector_type(4)));
typedef unsigned short u16;
typedef u16 u16x4 __attribute__((ext_vector_type(4)));
typedef u16 u16x8 __attribute__((ext_vector_type(8)));

__device__ __forceinline__ u16 f32_to_bf16(float f) {
  union { float f; uint32_t u; } x;
  x.f = f;
  uint32_t u = x.u;
  return (u16)((u + 0x7FFFu + ((u >> 16) & 1u)) >> 16);
}

// q' = bf16(q * tau[b] * scale), k' = bf16(k), delta' = delta * scale
__global__ __launch_bounds__(256) void prep_qkd(
    const float* __restrict__ q, const float* __restrict__ k,
    const float* __restrict__ tau, const float* __restrict__ delta,
    u16* __restrict__ qb, u16* __restrict__ kb, float* __restrict__ dl) {
  int idx = blockIdx.x * 256 + threadIdx.x;  // 0 .. 1048575
  int i4 = idx * 4;
  int b = i4 >> 20;                          // L_*H_*E_ = 2^20 per batch
  float ts = tau[b] * 0.125f;
  f32x4 qv = *(const f32x4*)(q + i4);
  f32x4 kv = *(const f32x4*)(k + i4);
  u16x4 qs, ks;
#pragma unroll
  for (int j = 0; j < 4; ++j) {
    qs[j] = f32_to_bf16(qv[j] * ts);
    ks[j] = f32_to_bf16(kv[j]);
  }
  *(u16x4*)(qb + i4) = qs;
  *(u16x4*)(kb + i4) = ks;
  if (idx < (B_ * S_) / 4) {
    f32x4 dv = *(const f32x4*)(delta + i4);
    f32x4 ds = {dv[0] * 0.125f, dv[1] * 0.125f, dv[2] * 0.125f, dv[3] * 0.125f};
    *(f32x4*)(dl + i4) = ds;
  }
}

// V [B,S,H,E] f32 -> V' [B,H,E,S] bf16 (tiled transpose)
__global__ __launch_bounds__(256) void prep_v(const float* __restrict__ v,
                                              u16* __restrict__ vb) {
  __shared__ float t[32][33];
  int bid = blockIdx.x;
  int et = bid & 1;
  int st = (bid >> 1) & 63;
  int h = (bid >> 7) & 7;
  int b = bid >> 10;
  int tx = threadIdx.x & 31;
  int ty = threadIdx.x >> 5;  // 0..7
#pragma unroll
  for (int k2 = 0; k2 < 4; ++k2) {
    int s = st * 32 + ty + 8 * k2;
    int e = et * 32 + tx;
    t[ty + 8 * k2][tx] = v[(((size_t)b * S_ + s) * H_ + h) * E_ + e];
  }
  __syncthreads();
#pragma unroll
  for (int k2 = 0; k2 < 4; ++k2) {
    int e = et * 32 + ty + 8 * k2;
    int s = st * 32 + tx;
    vb[(((size_t)b * H_ + h) * E_ + e) * S_ + s] = f32_to_bf16(t[tx][ty + 8 * k2]);
  }
}

// One WG per (b, h, 16-row q-tile). 4 waves.
__global__ __launch_bounds__(256, 2) void attn_main(
    const u16* __restrict__ qb, const u16* __restrict__ kb,
    const u16* __restrict__ vb, const float* __restrict__ dl,
    float* __restrict__ out, float* __restrict__ oa) {
  __shared__ _Float16 sc[QT][SROW];
  __shared__ float zinv[QT];

  // XCD-aware swizzle: 4096 blocks, 8 XCDs -> contiguous 512-block chunk per XCD
  int bid = blockIdx.x;
  int swz = (bid & 7) * 512 + (bid >> 3);
  int b = swz >> 10;
  int h = (swz >> 7) & 7;
  int qt = swz & 127;
  int m0 = qt * QT;

  int tid = threadIdx.x;
  int lane = tid & 63;
  int wave = tid >> 6;
  int l15 = lane & 15;
  int l4 = lane >> 4;

  // Q fragments (A): row = lane&15, k(e) = 8*(lane>>4)+j, two K=32 halves of E=64
  bf16x8 qa0, qa1;
  {
    const u16* qp = qb + (((size_t)b * L_ + (m0 + l15)) * H_ + h) * E_ + 8 * l4;
    qa0 = *(const bf16x8*)(qp);
    qa1 = *(const bf16x8*)(qp + 32);
  }

  // ---- Phase 1: QK^T -> fp16 logits in LDS. Each wave owns 512 s-columns. ----
  {
    const u16* kbase =
        kb + (((size_t)b * S_ + (wave * 512 + l15)) * H_ + h) * E_ + 8 * l4;
    const float* dbase = dl + b * S_ + wave * 512 + l15;
    int r0 = l4 * 4;
    int colbase = wave * 512 + l15;
#pragma unroll 2
    for (int c = 0; c < 32; ++c) {
      const u16* kp = kbase + (size_t)c * 16 * H_ * E_;
      f32x4 acc = {0.f, 0.f, 0.f, 0.f};
      acc = __builtin_amdgcn_mfma_f32_16x16x32_bf16(qa0, *(const bf16x8*)(kp), acc, 0, 0, 0);
      acc = __builtin_amdgcn_mfma_f32_16x16x32_bf16(qa1, *(const bf16x8*)(kp + 32), acc, 0, 0, 0);
      float d = dbase[c * 16];
      int col = colbase + c * 16;
      sc[r0 + 0][col] = (_Float16)(acc[0] + d);
      sc[r0 + 1][col] = (_Float16)(acc[1] + d);
      sc[r0 + 2][col] = (_Float16)(acc[2] + d);
      sc[r0 + 3][col] = (_Float16)(acc[3] + d);
    }
  }
  __syncthreads();

  // ---- Phase 2: row softmax (4 rows per wave), write a (fp32), p->LDS bf16 ----
  {
    const float LOG2E = 1.44269504088896f;
#pragma unroll 1
    for (int rr = 0; rr < 4; ++rr) {
      int row = wave * 4 + rr;
      f16x8 hv[4];
#pragma unroll
      for (int c2 = 0; c2 < 4; ++c2)
        hv[c2] = *(const f16x8*)&sc[row][c2 * 512 + lane * 8];
      float mx = -3.0e38f;
#pragma unroll
      for (int c2 = 0; c2 < 4; ++c2)
#pragma unroll
        for (int j = 0; j < 8; ++j) mx = fmaxf(mx, (float)hv[c2][j]);
      for (int o = 32; o > 0; o >>= 1) mx = fmaxf(mx, __shfl_xor(mx, o, 64));
      float p[32];
      float sum = 0.f;
#pragma unroll
      for (int c2 = 0; c2 < 4; ++c2)
#pragma unroll
        for (int j = 0; j < 8; ++j) {
          float e = __builtin_amdgcn_exp2f(((float)hv[c2][j] - mx) * LOG2E);
          p[c2 * 8 + j] = e;
          sum += e;
        }
      for (int o = 32; o > 0; o >>= 1) sum += __shfl_xor(sum, o, 64);
      float zi = 1.f / sum;
      if (lane == 0) zinv[row] = zi;
      float* arow = oa + ((size_t)(b * H_ + h) * L_ + (m0 + row)) * S_;
#pragma unroll
      for (int c2 = 0; c2 < 4; ++c2) {
        int sbase = c2 * 512 + lane * 8;
        f32x4 w0 = {p[c2 * 8 + 0] * zi, p[c2 * 8 + 1] * zi, p[c2 * 8 + 2] * zi,
                    p[c2 * 8 + 3] * zi};
        f32x4 w1 = {p[c2 * 8 + 4] * zi, p[c2 * 8 + 5] * zi, p[c2 * 8 + 6] * zi,
                    p[c2 * 8 + 7] * zi};
        *(f32x4*)(arow + sbase) = w0;
        *(f32x4*)(arow + sbase + 4) = w1;
        u16x8 pk;
#pragma unroll
        for (int j = 0; j < 8; ++j) pk[j] = f32_to_bf16(p[c2 * 8 + j]);
        *(u16x8*)((u16*)&sc[row][sbase]) = pk;
      }
    }
  }
  __syncthreads();

  // ---- Phase 3: out = (p @ V') * zinv. Wave owns 16 e-columns; full s sweep ----
  {
    int e0 = wave * 16;
    const u16* vbase =
        vb + ((size_t)(b * H_ + h) * E_ + e0 + l15) * S_ + 8 * l4;
    const u16* scb = (const u16*)&sc[l15][0] + 8 * l4;
    f32x4 oacc = {0.f, 0.f, 0.f, 0.f};
#pragma unroll 4
    for (int c = 0; c < 64; ++c) {
      bf16x8 pa = *(const bf16x8*)(scb + c * 32);
      bf16x8 vf = *(const bf16x8*)(vbase + c * 32);
      oacc = __builtin_amdgcn_mfma_f32_16x16x32_bf16(pa, vf, oacc, 0, 0, 0);
    }
    int r0 = l4 * 4;
#pragma unroll
    for (int r = 0; r < 4; ++r) {
      int row = r0 + r;
      out[(((size_t)b * L_ + (m0 + row)) * H_ + h) * E_ + e0 + l15] =
          oacc[r] * zinv[row];
    }
  }
}

extern "C" void kernel_launch(void* const* d_in, const int* in_sizes, int n_in,
                              void* d_out, int out_size, void* d_ws, size_t ws_size,
                              hipStream_t stream) {
  (void)in_sizes; (void)n_in; (void)out_size;
  const float* q = (const float*)d_in[0];
  const float* k = (const float*)d_in[1];
  const float* v = (const float*)d_in[2];
  const float* tau = (const float*)d_in[3];
  const float* delta = (const float*)d_in[4];
  float* out = (float*)d_out;
  float* oa = out + (size_t)B_ * L_ * H_ * E_;

  const size_t NQ = (size_t)B_ * L_ * H_ * E_;  // 4194304
  u16* qb = (u16*)d_ws;
  u16* kb = qb + NQ;
  u16* vb = kb + NQ;
  float* dl = (float*)(vb + NQ);
  size_t need = 3 * NQ * sizeof(u16) + (size_t)B_ * S_ * sizeof(float);
  if (ws_size < need) return;

  prep_qkd<<<4096, 256, 0, stream>>>(q, k, tau, delta, qb, kb, dl);
  prep_v<<<4096, 256, 0, stream>>>(v, vb);
  attn_main<<<4096, 256, 0, stream>>>(qb, kb, vb, dl, out, oa);
}